// Round 15
// baseline (291.907 us; speedup 1.0000x reference)
//
#include <hip/hip_runtime.h>
#include <hip/hip_bf16.h>
#include <stdint.h>

// Sizes: BS=64, M=1000, CLIP=512, D=512, N_WAYS=20, N_Z=8
// out = [logits (8,64,1000,20) | z (8,64,20,512) | mu (64,20,512) | scale (64,20,512)]

typedef __attribute__((ext_vector_type(8))) short short8;
typedef __attribute__((ext_vector_type(4))) float f32x4;

__device__ __forceinline__ float gelu_f(float x) {
    return 0.5f * x * (1.0f + erff(x * 0.70710678118654752440f));
}
__device__ __forceinline__ float softplus_f(float x) {
    return fmaxf(x, 0.0f) + log1pf(expf(-fabsf(x)));
}
__device__ __forceinline__ uint32_t cvt2(float a, float b) {  // pack 2 bf16 (RNE)
    __hip_bfloat162 h;
    h.x = __float2bfloat16(a);
    h.y = __float2bfloat16(b);
    uint32_t u; __builtin_memcpy(&u, &h, 4); return u;
}
__device__ __forceinline__ unsigned short f2bfu(float f) {
    __hip_bfloat16 h = __float2bfloat16(f);
    unsigned short u; __builtin_memcpy(&u, &h, 2); return u;
}
__device__ __forceinline__ float bfu2f(unsigned short u) {
    uint32_t v = (uint32_t)u << 16; float f; __builtin_memcpy(&f, &v, 4); return f;
}

// ---------------- threefry2x32 (partitionable) ----------------
__device__ __forceinline__ void threefry2x32(uint32_t k0, uint32_t k1,
                                             uint32_t x0, uint32_t x1,
                                             uint32_t& o0, uint32_t& o1) {
    uint32_t ks[3] = {k0, k1, k0 ^ k1 ^ 0x1BD11BDAu};
    x0 += ks[0]; x1 += ks[1];
    const uint32_t rot[8] = {13,15,26,6,17,29,16,24};
#pragma unroll
    for (int i = 0; i < 5; i++) {
#pragma unroll
        for (int j = 0; j < 4; j++) {
            uint32_t r = rot[(i & 1) * 4 + j];
            x0 += x1;
            x1 = (x1 << r) | (x1 >> (32 - r));
            x1 ^= x0;
        }
        x0 += ks[(i + 1) % 3];
        x1 += ks[(i + 2) % 3] + (uint32_t)(i + 1);
    }
    o0 = x0; o1 = x1;
}

__device__ __forceinline__ float bits_to_normal(uint32_t b) {
    float f = __uint_as_float((b >> 9) | 0x3F800000u) - 1.0f;
    const float lo = __uint_as_float(0xBF7FFFFFu);
    float u = fmaxf(lo, f * 2.0f + lo);
    return 1.41421356237309504880f * erfinvf(u);
}

// ---------------- po_k: prep (673 blocks) + onehot K-split GEMM (1024 blocks) --
__global__ __launch_bounds__(256) void po_k(
    const float* __restrict__ Wp, const float* __restrict__ Wa1,
    const float* __restrict__ Wa2, const float* __restrict__ Wd1,
    const float* __restrict__ Wd2, const float* __restrict__ bp,
    const float* __restrict__ bd2, const int* __restrict__ y,
    const float* __restrict__ xc,
    unsigned short* __restrict__ WpTb, unsigned short* __restrict__ Wa1Tb,
    unsigned short* __restrict__ Wa2Tb, unsigned short* __restrict__ WdT1b,
    unsigned short* __restrict__ Gtb,
    float* __restrict__ bv, float* __restrict__ w2bp,
    float* __restrict__ c0, float* __restrict__ cnt,
    float* __restrict__ Apart)
{
    __shared__ __align__(16) char sm[24576];
    __shared__ int lc[256];
    __shared__ float ws4[4];
    const int f = blockIdx.x;
    const int tid = threadIdx.x;

    if (f < 320) {  // ---- transpose fp32 [512 x C] -> bf16 [C x 512]
        float (*T)[65] = reinterpret_cast<float(*)[65]>(sm);
        const float* src; unsigned short* dst; int C, t, xb, yb;
        if (f < 64)       { src = Wp;  dst = WpTb;  C = 512;  t = f;       xb = t & 7;  yb = t >> 3; }
        else if (f < 128) { src = Wa1; dst = Wa1Tb; C = 512;  t = f - 64;  xb = t & 7;  yb = t >> 3; }
        else if (f < 256) { src = Wa2; dst = Wa2Tb; C = 1024; t = f - 128; xb = t & 15; yb = t >> 4; }
        else              { src = Wd1; dst = WdT1b; C = 512;  t = f - 256; xb = t & 7;  yb = t >> 3; }
        const int r0 = yb * 64, cc0 = xb * 64;
        const int rr = tid >> 4, cc = (tid & 15) * 4;
#pragma unroll
        for (int l = 0; l < 4; l++) {
            int row = rr + l * 16;
            float4 v = *(const float4*)&src[(size_t)(r0 + row) * C + cc0 + cc];
            T[row][cc] = v.x; T[row][cc+1] = v.y; T[row][cc+2] = v.z; T[row][cc+3] = v.w;
        }
        __syncthreads();
#pragma unroll
        for (int l = 0; l < 4; l++) {
            int n = rr + l * 16;
            uint2 u;
            u.x = cvt2(T[cc][n], T[cc+1][n]);
            u.y = cvt2(T[cc+2][n], T[cc+3][n]);
            *(uint2*)&dst[(size_t)(cc0 + n) * 512 + r0 + cc] = u;
        }
    } else if (f < 576) {  // ---- row dots (wave per row)
        const float* W = (f < 448) ? Wp : Wd2;
        const float* v = (f < 448) ? bd2 : bp;
        float* o = (f < 448) ? bv : w2bp;
        int t = (f < 448) ? f - 320 : f - 448;
        int wave = tid >> 6, lane = tid & 63;
        int r = t * 4 + wave;
        const float* row = W + (size_t)r * 512 + lane * 8;
        float4 x0 = *(const float4*)row;
        float4 x1 = *(const float4*)(row + 4);
        float4 v0 = *(const float4*)&v[lane * 8];
        float4 v1 = *(const float4*)&v[lane * 8 + 4];
        float s = x0.x*v0.x + x0.y*v0.y + x0.z*v0.z + x0.w*v0.w
                + x1.x*v1.x + x1.y*v1.y + x1.z*v1.z + x1.w*v1.w;
#pragma unroll
        for (int off = 32; off > 0; off >>= 1) s += __shfl_down(s, off, 64);
        if (lane == 0) o[r] = s;
    } else if (f == 576) {  // ---- c0 = bp . bd2
        float s = bp[tid] * bd2[tid] + bp[tid + 256] * bd2[tid + 256];
#pragma unroll
        for (int off = 32; off > 0; off >>= 1) s += __shfl_down(s, off, 64);
        int wave = tid >> 6, lane = tid & 63;
        if (lane == 0) ws4[wave] = s;
        __syncthreads();
        if (tid == 0) c0[0] = ws4[0] + ws4[1] + ws4[2] + ws4[3];
    } else if (f < 641) {  // ---- class counts, exact int atomics
        int b = f - 577;
        if (tid < 32) lc[tid] = 0;
        __syncthreads();
        for (int m = tid; m < 1000; m += 256)
            atomicAdd(&lc[y[b * 1000 + m]], 1);
        __syncthreads();
        if (tid < 20) cnt[b * 20 + tid] = (float)lc[tid];
    } else if (f < 673) {  // ---- G = Wp @ Wd2^T (MFMA)
        unsigned short* As = (unsigned short*)sm;
        unsigned short* Bs = (unsigned short*)(sm + 8192);
        const int g = f - 641;
        const int lane = tid & 63, w = tid >> 6;
        const int row0 = (g >> 2) * 64, col0 = (g & 3) * 128;
        f32x4 acc[4][2] = {};
        for (int k0 = 0; k0 < 512; k0 += 64) {
            {
                int row = tid >> 2, cs = (tid & 3) * 16;
                int swz = (row & 7) << 4;
                const float* src = Wp + (size_t)(row0 + row) * 512 + k0 + cs;
#pragma unroll
                for (int j = 0; j < 2; j++) {
                    float4 v0 = *(const float4*)(src + j * 8);
                    float4 v1 = *(const float4*)(src + j * 8 + 4);
                    uint4 u;
                    u.x = cvt2(v0.x, v0.y); u.y = cvt2(v0.z, v0.w);
                    u.z = cvt2(v1.x, v1.y); u.w = cvt2(v1.z, v1.w);
                    *(uint4*)((char*)As + row * 128 + (((cs + j * 8) * 2) ^ swz)) = u;
                }
            }
            {
                int row = tid >> 1, cs = (tid & 1) * 32;
                int swz = (row & 7) << 4;
                const float* src = Wd2 + (size_t)(col0 + row) * 512 + k0 + cs;
#pragma unroll
                for (int j = 0; j < 4; j++) {
                    float4 v0 = *(const float4*)(src + j * 8);
                    float4 v1 = *(const float4*)(src + j * 8 + 4);
                    uint4 u;
                    u.x = cvt2(v0.x, v0.y); u.y = cvt2(v0.z, v0.w);
                    u.z = cvt2(v1.x, v1.y); u.w = cvt2(v1.z, v1.w);
                    *(uint4*)((char*)Bs + row * 128 + (((cs + j * 8) * 2) ^ swz)) = u;
                }
            }
            __syncthreads();
#pragma unroll
            for (int ks = 0; ks < 2; ks++) {
                short8 a[4], bb[2];
#pragma unroll
                for (int mi = 0; mi < 4; mi++) {
                    int r = mi * 16 + (lane & 15);
                    a[mi] = *(const short8*)((const char*)As + r * 128 +
                              (((ks * 32 + (lane >> 4) * 8) * 2) ^ ((r & 7) << 4)));
                }
#pragma unroll
                for (int ni = 0; ni < 2; ni++) {
                    int n = w * 32 + ni * 16 + (lane & 15);
                    bb[ni] = *(const short8*)((const char*)Bs + n * 128 +
                              (((ks * 32 + (lane >> 4) * 8) * 2) ^ ((n & 7) << 4)));
                }
#pragma unroll
                for (int mi = 0; mi < 4; mi++)
#pragma unroll
                    for (int ni = 0; ni < 2; ni++)
                        acc[mi][ni] = __builtin_amdgcn_mfma_f32_16x16x32_bf16(a[mi], bb[ni], acc[mi][ni], 0, 0, 0);
            }
            __syncthreads();
        }
#pragma unroll
        for (int mi = 0; mi < 4; mi++)
#pragma unroll
            for (int ni = 0; ni < 2; ni++) {
                int c = col0 + w * 32 + ni * 16 + (lane & 15);
#pragma unroll
                for (int j = 0; j < 4; j++) {
                    int r = row0 + mi * 16 + (lane >> 4) * 4 + j;
                    Gtb[(size_t)r * 512 + c] = f2bfu(acc[mi][ni][j]);
                }
            }
    } else {  // ---- onehot K-split partials
        unsigned short* Xs = (unsigned short*)sm;
        int* ys = lc;
        const int f2 = f - 673;
        const int chb = (f2 & 3) * 128;
        const int mc = (f2 >> 2) & 3;
        const int b = f2 >> 4;
        const int m00 = mc * 256;
        const int lane = tid & 63, w = tid >> 6;
        const int chs = w * 32;
        {
            int mg = m00 + tid;
            ys[tid] = (mg < 1000) ? y[b * 1000 + mg] : -1;
        }
        f32x4 acc[2][2] = {};
        for (int step = 0; step < 4; step++) {
            const int k0 = step * 64;
            int m = m00 + k0 + lane; if (m > 999) m = 999;
            const float* src = xc + ((size_t)b * 1000 + m) * 512 + chb + chs;
            float x[32];
#pragma unroll
            for (int j8 = 0; j8 < 8; j8++) {
                float4 v = *(const float4*)(src + j8 * 4);
                x[j8*4+0]=v.x; x[j8*4+1]=v.y; x[j8*4+2]=v.z; x[j8*4+3]=v.w;
            }
            __syncthreads();
#pragma unroll
            for (int j = 0; j < 32; j++) {
                int ch = chs + j;
                *(unsigned short*)((char*)Xs + ch * 128 + ((lane * 2) ^ ((ch & 7) << 4)))
                    = f2bfu(x[j]);
            }
            __syncthreads();
#pragma unroll
            for (int ks = 0; ks < 2; ks++) {
                int kb = ks * 32 + (lane >> 4) * 8;
                int4 yv0 = *(const int4*)&ys[k0 + kb];
                int4 yv1 = *(const int4*)&ys[k0 + kb + 4];
                int ya[8] = {yv0.x, yv0.y, yv0.z, yv0.w, yv1.x, yv1.y, yv1.z, yv1.w};
                short8 a[2];
#pragma unroll
                for (int mi = 0; mi < 2; mi++) {
                    int cls = mi * 16 + (lane & 15);
#pragma unroll
                    for (int e = 0; e < 8; e++)
                        a[mi][e] = (short)((ya[e] == cls) ? 0x3F80 : 0);
                }
                short8 bb[2];
#pragma unroll
                for (int ni = 0; ni < 2; ni++) {
                    int ch = chs + ni * 16 + (lane & 15);
                    bb[ni] = *(const short8*)((const char*)Xs + ch * 128 +
                               ((kb * 2) ^ ((ch & 7) << 4)));
                }
#pragma unroll
                for (int mi = 0; mi < 2; mi++)
#pragma unroll
                    for (int ni = 0; ni < 2; ni++)
                        acc[mi][ni] = __builtin_amdgcn_mfma_f32_16x16x32_bf16(a[mi], bb[ni], acc[mi][ni], 0, 0, 0);
            }
        }
        float* dst = Apart + (size_t)mc * 655360;
#pragma unroll
        for (int mi = 0; mi < 2; mi++) {
#pragma unroll
            for (int ni = 0; ni < 2; ni++) {
                int ch = chb + chs + ni * 16 + (lane & 15);
#pragma unroll
                for (int j = 0; j < 4; j++) {
                    int cls = mi * 16 + (lane >> 4) * 4 + j;
                    if (cls < 20)
                        dst[((size_t)b * 20 + cls) * 512 + ch] = acc[mi][ni][j];
                }
            }
        }
    }
}

// ---------------- chain_k: fused comb -> h -> stats (mu, sc) ----------------
// 20 blocks x 512 thr. Block owns 64 rows of the 1280-row space.
// comb, h live in LDS; B operands direct from global (L2-resident).
__global__ __launch_bounds__(512) void chain_k(
    const float* __restrict__ Apart,          // 4 fp32 partial sets
    const unsigned short* __restrict__ WpT,
    const unsigned short* __restrict__ Wa1T,
    const unsigned short* __restrict__ Wa2T,  // [1024 n][512 k]
    const float* __restrict__ bp, const float* __restrict__ cnt,
    const float* __restrict__ ba1, const float* __restrict__ ba2,
    float* __restrict__ mu, float* __restrict__ sc)
{
    __shared__ unsigned short As[64 * 64];    // 8 KB staging
    __shared__ unsigned short Cw[64 * 512];   // 64 KB comb (1024B rows, swz)
    __shared__ unsigned short Hw[64 * 512];   // 64 KB h
    const int r0 = blockIdx.x * 64;
    const int tid = threadIdx.x, lane = tid & 63, w = tid >> 6;
    const int col0 = w * 64;

    // ---- phase 1: comb = relu(A@WpT + cnt[r]*bp[c]) -> Cw ----
    {
        f32x4 acc[4][4] = {};
        for (int k0 = 0; k0 < 512; k0 += 64) {
            {
                int row = tid >> 3, cs = (tid & 7) * 8;
                int swz = (row & 7) << 4;
                const float* p = Apart + (size_t)(r0 + row) * 512 + k0 + cs;
                float4 s0 = *(const float4*)p;
                float4 s1 = *(const float4*)(p + 4);
#pragma unroll
                for (int q = 1; q < 4; q++) {
                    const float* pp = p + (size_t)q * 655360;
                    float4 v0 = *(const float4*)pp, v1 = *(const float4*)(pp + 4);
                    s0.x += v0.x; s0.y += v0.y; s0.z += v0.z; s0.w += v0.w;
                    s1.x += v1.x; s1.y += v1.y; s1.z += v1.z; s1.w += v1.w;
                }
                uint4 u;
                u.x = cvt2(s0.x, s0.y); u.y = cvt2(s0.z, s0.w);
                u.z = cvt2(s1.x, s1.y); u.w = cvt2(s1.z, s1.w);
                *(uint4*)((char*)As + row * 128 + ((cs * 2) ^ swz)) = u;
            }
            __syncthreads();
#pragma unroll
            for (int ks = 0; ks < 2; ks++) {
                int kb = ks * 32 + (lane >> 4) * 8;
                short8 a[4], bb[4];
#pragma unroll
                for (int mi = 0; mi < 4; mi++) {
                    int r = mi * 16 + (lane & 15);
                    a[mi] = *(const short8*)((const char*)As + r * 128 +
                              ((kb * 2) ^ ((r & 7) << 4)));
                }
#pragma unroll
                for (int ni = 0; ni < 4; ni++) {
                    int n = col0 + ni * 16 + (lane & 15);
                    bb[ni] = *(const short8*)(WpT + (size_t)n * 512 + k0 + kb);
                }
#pragma unroll
                for (int mi = 0; mi < 4; mi++)
#pragma unroll
                    for (int ni = 0; ni < 4; ni++)
                        acc[mi][ni] = __builtin_amdgcn_mfma_f32_16x16x32_bf16(a[mi], bb[ni], acc[mi][ni], 0, 0, 0);
            }
            __syncthreads();
        }
#pragma unroll
        for (int mi = 0; mi < 4; mi++) {
#pragma unroll
            for (int ni = 0; ni < 4; ni++) {
                int c = col0 + ni * 16 + (lane & 15);
                float bpc = bp[c];
#pragma unroll
                for (int j = 0; j < 4; j++) {
                    int r = mi * 16 + (lane >> 4) * 4 + j;
                    float v = acc[mi][ni][j] + cnt[r0 + r] * bpc;
                    *(unsigned short*)((char*)Cw + r * 1024 + ((c * 2) ^ ((r & 7) << 4)))
                        = f2bfu(fmaxf(v, 0.f));
                }
            }
        }
    }
    __syncthreads();

    // ---- phase 2: h = gelu(comb@Wa1T + ba1) -> Hw ----
    {
        f32x4 acc[4][4] = {};
        for (int k0 = 0; k0 < 512; k0 += 64) {
#pragma unroll
            for (int ks = 0; ks < 2; ks++) {
                int kb = ks * 32 + (lane >> 4) * 8;
                short8 a[4], bb[4];
#pragma unroll
                for (int mi = 0; mi < 4; mi++) {
                    int r = mi * 16 + (lane & 15);
                    a[mi] = *(const short8*)((const char*)Cw + r * 1024 +
                              (((k0 + kb) * 2) ^ ((r & 7) << 4)));
                }
#pragma unroll
                for (int ni = 0; ni < 4; ni++) {
                    int n = col0 + ni * 16 + (lane & 15);
                    bb[ni] = *(const short8*)(Wa1T + (size_t)n * 512 + k0 + kb);
                }
#pragma unroll
                for (int mi = 0; mi < 4; mi++)
#pragma unroll
                    for (int ni = 0; ni < 4; ni++)
                        acc[mi][ni] = __builtin_amdgcn_mfma_f32_16x16x32_bf16(a[mi], bb[ni], acc[mi][ni], 0, 0, 0);
            }
        }
        __syncthreads();   // all Cw reads done before Hw writes (aliasing-safe: distinct bufs, but keep order clean)
#pragma unroll
        for (int mi = 0; mi < 4; mi++) {
#pragma unroll
            for (int ni = 0; ni < 4; ni++) {
                int c = col0 + ni * 16 + (lane & 15);
                float bvv = ba1[c];
#pragma unroll
                for (int j = 0; j < 4; j++) {
                    int r = mi * 16 + (lane >> 4) * 4 + j;
                    float v = gelu_f(acc[mi][ni][j] + bvv);
                    *(unsigned short*)((char*)Hw + r * 1024 + ((c * 2) ^ ((r & 7) << 4)))
                        = f2bfu(v);
                }
            }
        }
    }
    __syncthreads();

    // ---- phase 3: stats = h@Wa2T + ba2; 2 col-passes (N=1024) ----
#pragma unroll
    for (int p = 0; p < 2; p++) {
        f32x4 acc[4][4] = {};
        const int cg0 = p * 512 + col0;
        for (int k0 = 0; k0 < 512; k0 += 64) {
#pragma unroll
            for (int ks = 0; ks < 2; ks++) {
                int kb = ks * 32 + (lane >> 4) * 8;
                short8 a[4], bb[4];
#pragma unroll
                for (int mi = 0; mi < 4; mi++) {
                    int r = mi * 16 + (lane & 15);
                    a[mi] = *(const short8*)((const char*)Hw + r * 1024 +
                              (((k0 + kb) * 2) ^ ((r & 7) << 4)));
                }
#pragma unroll
                for (int ni = 0; ni < 4; ni++) {
                    int n = cg0 + ni * 16 + (lane & 15);
                    bb[ni] = *(const short8*)(Wa2T + (size_t)n * 512 + k0 + kb);
                }
#pragma unroll
                for (int mi = 0; mi < 4; mi++)
#pragma unroll
                    for (int ni = 0; ni < 4; ni++)
                        acc[mi][ni] = __builtin_amdgcn_mfma_f32_16x16x32_bf16(a[mi], bb[ni], acc[mi][ni], 0, 0, 0);
            }
        }
#pragma unroll
        for (int mi = 0; mi < 4; mi++) {
#pragma unroll
            for (int ni = 0; ni < 4; ni++) {
                int cg = cg0 + ni * 16 + (lane & 15);
                float bvv = ba2[cg];
                int cl = cg - p * 512;
#pragma unroll
                for (int j = 0; j < 4; j++) {
                    int r = r0 + mi * 16 + (lane >> 4) * 4 + j;
                    float v = acc[mi][ni][j] + bvv;
                    if (p == 0) mu[(size_t)r * 512 + cl] = v;
                    else        sc[(size_t)r * 512 + cl] = 0.01f + 0.99f * softplus_f(v);
                }
            }
        }
    }
}

// ---------------- z = mu + scale*eps ; emits fp32 z + bf16 zb ----------------
__global__ __launch_bounds__(256) void z2_k(const float* __restrict__ mu,
                                            const float* __restrict__ sc,
                                            float* __restrict__ z,
                                            unsigned short* __restrict__ zb) {
    const uint32_t NH = 2621440u;
    uint32_t i = blockIdx.x * 256u + threadIdx.x;
    if (i >= NH) return;
    uint32_t t0 = 2u * i;
    uint32_t o0, o1, p0, p1;
    threefry2x32(0u, 42u, 0u, t0, o0, o1);
    threefry2x32(0u, 42u, 0u, t0 + 1u, p0, p1);
    uint32_t r0 = t0 % 655360u;
    float2 mv = *(const float2*)&mu[r0];
    float2 sv = *(const float2*)&sc[r0];
    float z0 = mv.x + sv.x * bits_to_normal(o0 ^ o1);
    float z1 = mv.y + sv.y * bits_to_normal(p0 ^ p1);
    float2 zo; zo.x = z0; zo.y = z1;
    *(float2*)&z[t0] = zo;
    *(uint32_t*)&zb[t0] = cvt2(z0, z1);
}

// ---------------- wgv_k: fused Wg -> V, beta ----------------
__global__ __launch_bounds__(512) void wgv_k(const unsigned short* __restrict__ zb,
                                             const unsigned short* __restrict__ Wd1T,
                                             const unsigned short* __restrict__ Gt,
                                             const float* __restrict__ bd1,
                                             const float* __restrict__ bv,
                                             const float* __restrict__ w2bp,
                                             const float* __restrict__ c0,
                                             unsigned short* __restrict__ Vbf,
                                             float* __restrict__ beta) {
    __shared__ unsigned short Wg[64 * 512];
    __shared__ unsigned short As[64 * 64];
    const int r0 = blockIdx.x * 64;
    const int tid = threadIdx.x, lane = tid & 63, w = tid >> 6;
    const int col0 = w * 64;

    f32x4 acc[4][4] = {};
    for (int k0 = 0; k0 < 512; k0 += 64) {
        {
            int row = tid >> 3, cs = (tid & 7) * 8;
            int swz = (row & 7) << 4;
            uint4 u = *(const uint4*)(zb + (size_t)(r0 + row) * 512 + k0 + cs);
            *(uint4*)((char*)As + row * 128 + ((cs * 2) ^ swz)) = u;
        }
        __syncthreads();
#pragma unroll
        for (int ks = 0; ks < 2; ks++) {
            int kb = ks * 32 + (lane >> 4) * 8;
            short8 a[4], bb[4];
#pragma unroll
            for (int mi = 0; mi < 4; mi++) {
                int r = mi * 16 + (lane & 15);
                a[mi] = *(const short8*)((const char*)As + r * 128 +
                          ((kb * 2) ^ ((r & 7) << 4)));
            }
#pragma unroll
            for (int ni = 0; ni < 4; ni++) {
                int n = col0 + ni * 16 + (lane & 15);
                bb[ni] = *(const short8*)(Wd1T + (size_t)n * 512 + k0 + kb);
            }
#pragma unroll
            for (int mi = 0; mi < 4; mi++)
#pragma unroll
                for (int ni = 0; ni < 4; ni++)
                    acc[mi][ni] = __builtin_amdgcn_mfma_f32_16x16x32_bf16(a[mi], bb[ni], acc[mi][ni], 0, 0, 0);
        }
        __syncthreads();
    }
#pragma unroll
    for (int mi = 0; mi < 4; mi++) {
#pragma unroll
        for (int ni = 0; ni < 4; ni++) {
            int c = col0 + ni * 16 + (lane & 15);
            float bvv = bd1[c];
#pragma unroll
            for (int j = 0; j < 4; j++) {
                int r = mi * 16 + (lane >> 4) * 4 + j;
                float v = gelu_f(acc[mi][ni][j] + bvv);
                *(unsigned short*)((char*)Wg + r * 1024 + ((c * 2) ^ ((r & 7) << 4)))
                    = f2bfu(v);
            }
        }
    }
    __syncthreads();

    {
        int row = tid >> 3, p = tid & 7;
        const char* base = (const char*)Wg + row * 1024;
        int swz = (row & 7) << 4;
        float s = 0.f;
#pragma unroll
        for (int j = 0; j < 64; j++) {
            int c = p * 64 + j;
            s += bfu2f(*(const unsigned short*)(base + ((c * 2) ^ swz))) * w2bp[c];
        }
#pragma unroll
        for (int off = 4; off > 0; off >>= 1) s += __shfl_down(s, off, 64);
        if (p == 0) beta[r0 + row] = s + c0[0];
    }

    f32x4 acc2[4][4] = {};
    for (int k0 = 0; k0 < 512; k0 += 64) {
#pragma unroll
        for (int ks = 0; ks < 2; ks++) {
            int kb = ks * 32 + (lane >> 4) * 8;
            short8 a[4], bb[4];
#pragma unroll
            for (int mi = 0; mi < 4; mi++) {
                int r = mi * 16 + (lane & 15);
                a[mi] = *(const short8*)((const char*)Wg + r * 1024 +
                          (((k0 + kb) * 2) ^ ((r & 7) << 4)));
            }
#pragma unroll
            for (int ni = 0; ni < 4; ni++) {
                int n = col0 + ni * 16 + (lane & 15);
                bb[ni] = *(const short8*)(Gt + (size_t)n * 512 + k0 + kb);
            }
#pragma unroll
            for (int mi = 0; mi < 4; mi++)
#pragma unroll
                for (int ni = 0; ni < 4; ni++)
                    acc2[mi][ni] = __builtin_amdgcn_mfma_f32_16x16x32_bf16(a[mi], bb[ni], acc2[mi][ni], 0, 0, 0);
        }
    }
#pragma unroll
    for (int mi = 0; mi < 4; mi++) {
#pragma unroll
        for (int ni = 0; ni < 4; ni++) {
            int c = col0 + ni * 16 + (lane & 15);
            float bvv = bv[c];
#pragma unroll
            for (int j = 0; j < 4; j++) {
                int r = r0 + mi * 16 + (lane >> 4) * 4 + j;
                Vbf[(size_t)r * 512 + c] = f2bfu(acc2[mi][ni][j] + bvv);
            }
        }
    }
}

// ---------------- logits v4: dbuf V staging, 1 barrier/k-step ---------------
__global__ __launch_bounds__(512) void logits_mfma4_k(const float* __restrict__ Xq,
                                                      const unsigned short* __restrict__ Vb,
                                                      const float* __restrict__ beta,
                                                      float* __restrict__ out) {
    __shared__ unsigned short Vs[2][160 * 64];
    __shared__ float bs[160];
    const int u = blockIdx.x + 8 * blockIdx.y;
    const int xcd = u & 7, idx = u >> 3;
    const int b = (idx & 7) * 8 + xcd;
    const int qh = idx >> 3;
    const int tid = threadIdx.x, lane = tid & 63, w = tid >> 6;
    const int wq = w >> 1, wn = w & 1;

    if (tid < 160) {
        int s = tid / 20, n = tid - s * 20;
        bs[tid] = beta[(size_t)(s * 64 + b) * 20 + n];
    }

    auto stageV = [&](int buf, int k0) {
        for (int c = tid; c < 640; c += 512) {
            int row = c >> 2, off = (c & 3) * 32;
            int sdiv = row / 20;
            int row_g = row + sdiv * 1260 + b * 20;
            const unsigned short* src = Vb + (size_t)row_g * 512 + k0 + (c & 3) * 16;
            uint4 u0 = *(const uint4*)src;
            uint4 u1 = *(const uint4*)(src + 8);
            int swz = (row & 7) << 4;
            char* base = (char*)&Vs[buf][0] + row * 128;
            *(uint4*)(base + (off ^ swz)) = u0;
            *(uint4*)(base + ((off + 16) ^ swz)) = u1;
        }
    };

    const int klane = (lane >> 4) * 8;
    const float* xp[2];
    int qb[2];
#pragma unroll
    for (int qs = 0; qs < 2; qs++) {
        qb[qs] = qh * 128 + wq * 32 + qs * 16;
        int qr = qb[qs] + (lane & 15);
        if (qr > 999) qr = 999;
        xp[qs] = Xq + ((size_t)b * 1000 + qr) * 512 + klane;
    }
    int vrow[5], vswz[5];
#pragma unroll
    for (int nf = 0; nf < 5; nf++) {
        int rr = wn * 80 + nf * 16 + (lane & 15);
        vrow[nf] = rr * 128;
        vswz[nf] = (rr & 7) << 4;
    }

    stageV(0, 0);
    __syncthreads();

    f32x4 acc[2][5] = {};
    int cur = 0;
    for (int step = 0; step < 8; step++) {
        const int k0 = step * 64;
        if (step < 7) stageV(cur ^ 1, k0 + 64);
        const char* vbase = (const char*)&Vs[cur][0];
#pragma unroll
        for (int ks = 0; ks < 2; ks++) {
            int kb = (ks * 32 + klane) * 2;
            short8 bf[5];
#pragma unroll
            for (int nf = 0; nf < 5; nf++)
                bf[nf] = *(const short8*)(vbase + vrow[nf] + (kb ^ vswz[nf]));
            short8 af[2];
#pragma unroll
            for (int qs = 0; qs < 2; qs++) {
                const float* p = xp[qs] + k0 + ks * 32;
                float4 v0 = *(const float4*)p;
                float4 v1 = *(const float4*)(p + 4);
                uint4 uu;
                uu.x = cvt2(v0.x, v0.y); uu.y = cvt2(v0.z, v0.w);
                uu.z = cvt2(v1.x, v1.y); uu.w = cvt2(v1.z, v1.w);
                __builtin_memcpy(&af[qs], &uu, 16);
            }
#pragma unroll
            for (int qs = 0; qs < 2; qs++)
#pragma unroll
                for (int nf = 0; nf < 5; nf++)
                    acc[qs][nf] = __builtin_amdgcn_mfma_f32_16x16x32_bf16(af[qs], bf[nf], acc[qs][nf], 0, 0, 0);
        }
        __syncthreads();
        cur ^= 1;
    }

#pragma unroll
    for (int nf = 0; nf < 5; nf++) {
        int rl = wn * 80 + nf * 16 + (lane & 15);
        int s = rl / 20, n = rl - s * 20;
        float bb = bs[rl];
        size_t ob = (size_t)(s * 64 + b) * 20000;
#pragma unroll
        for (int qs = 0; qs < 2; qs++) {
#pragma unroll
            for (int j = 0; j < 4; j++) {
                int q = qb[qs] + (lane >> 4) * 4 + j;
                if (q < 1000)
                    out[ob + (size_t)q * 20 + n] = acc[qs][nf][j] + bb;
            }
        }
    }
}

extern "C" void kernel_launch(void* const* d_in, const int* in_sizes, int n_in,
                              void* d_out, int out_size, void* d_ws, size_t ws_size,
                              hipStream_t stream) {
    const float* x_context = (const float*)d_in[0];
    const int*   y_context = (const int*)d_in[1];
    const float* x_query   = (const float*)d_in[2];
    const float* Wp  = (const float*)d_in[3];
    const float* bp  = (const float*)d_in[4];
    const float* Wa1 = (const float*)d_in[5];
    const float* ba1 = (const float*)d_in[6];
    const float* Wa2 = (const float*)d_in[7];
    const float* ba2 = (const float*)d_in[8];
    const float* Wd1 = (const float*)d_in[9];
    const float* bd1 = (const float*)d_in[10];
    const float* Wd2 = (const float*)d_in[11];
    const float* bd2 = (const float*)d_in[12];

    float* out    = (float*)d_out;
    float* logits = out;                   // 10,240,000 f
    float* z      = out + 10240000;        // 5,242,880 f
    float* mu     = out + 15482880;        // 655,360 f
    float* sc     = out + 16138240;        // 655,360 f

    // workspace layout
    float* ws   = (float*)d_ws;
    float* cnt  = ws;                       // 1,280 f
    float* beta = cnt + 1280;               // 10,240 f
    float* bv   = beta + 10240;             // 512 f
    float* w2bp = bv + 512;                 // 512 f
    float* c0   = w2bp + 512;               // 1 f (+pad)
    unsigned short* WpTb  = (unsigned short*)(c0 + 63);       // 262,144 sh
    unsigned short* Wa1Tb = WpTb + 262144;                    // 262,144 sh
    unsigned short* Wa2Tb = Wa1Tb + 262144;                   // 524,288 sh
    unsigned short* WdT1b = Wa2Tb + 524288;                   // 262,144 sh
    unsigned short* Gtb   = WdT1b + 262144;                   // 262,144 sh
    unsigned short* zb    = Gtb + 262144;                     // 5,242,880 sh
    unsigned short* Vbf   = zb + 5242880;                     // 5,242,880 sh
    float* big = (float*)(Vbf + 5242880);   // 4x655,360 f onehot partials

    // 0) prep + G + onehot partials
    po_k<<<dim3(1697), 256, 0, stream>>>(Wp, Wa1, Wa2, Wd1, Wd2, bp, bd2, y_context,
                                         x_context,
                                         WpTb, Wa1Tb, Wa2Tb, WdT1b, Gtb,
                                         bv, w2bp, c0, cnt, big);
    // 1) fused chain: comb -> h -> mu/sc
    chain_k<<<dim3(20), 512, 0, stream>>>(big, WpTb, Wa1Tb, Wa2Tb,
                                          bp, cnt, ba1, ba2, mu, sc);
    // 2) z (fp32 out) + zb (bf16)
    z2_k<<<dim3(10240), 256, 0, stream>>>(mu, sc, z, zb);
    // 3) Wg (LDS) -> V, beta
    wgv_k<<<dim3(160), 512, 0, stream>>>(zb, WdT1b, Gtb, bd1, bv, w2bp, c0, Vbf, beta);
    // 4) logits
    logits_mfma4_k<<<dim3(8, 64), 512, 0, stream>>>(x_query, Vbf, beta, logits);
}

// Round 16
// 215.001 us; speedup vs baseline: 1.3577x; 1.3577x over previous
//
#include <hip/hip_runtime.h>
#include <hip/hip_bf16.h>
#include <stdint.h>

// Sizes: BS=64, M=1000, CLIP=512, D=512, N_WAYS=20, N_Z=8
// out = [logits (8,64,1000,20) | z (8,64,20,512) | mu (64,20,512) | scale (64,20,512)]

typedef __attribute__((ext_vector_type(8))) short short8;
typedef __attribute__((ext_vector_type(4))) float f32x4;

__device__ __forceinline__ float gelu_f(float x) {
    return 0.5f * x * (1.0f + erff(x * 0.70710678118654752440f));
}
__device__ __forceinline__ float softplus_f(float x) {
    return fmaxf(x, 0.0f) + log1pf(expf(-fabsf(x)));
}
__device__ __forceinline__ uint32_t cvt2(float a, float b) {  // pack 2 bf16 (RNE)
    __hip_bfloat162 h;
    h.x = __float2bfloat16(a);
    h.y = __float2bfloat16(b);
    uint32_t u; __builtin_memcpy(&u, &h, 4); return u;
}
__device__ __forceinline__ unsigned short f2bfu(float f) {
    __hip_bfloat16 h = __float2bfloat16(f);
    unsigned short u; __builtin_memcpy(&u, &h, 2); return u;
}
__device__ __forceinline__ float bfu2f(unsigned short u) {
    uint32_t v = (uint32_t)u << 16; float f; __builtin_memcpy(&f, &v, 4); return f;
}

// ---------------- threefry2x32 (partitionable) ----------------
__device__ __forceinline__ void threefry2x32(uint32_t k0, uint32_t k1,
                                             uint32_t x0, uint32_t x1,
                                             uint32_t& o0, uint32_t& o1) {
    uint32_t ks[3] = {k0, k1, k0 ^ k1 ^ 0x1BD11BDAu};
    x0 += ks[0]; x1 += ks[1];
    const uint32_t rot[8] = {13,15,26,6,17,29,16,24};
#pragma unroll
    for (int i = 0; i < 5; i++) {
#pragma unroll
        for (int j = 0; j < 4; j++) {
            uint32_t r = rot[(i & 1) * 4 + j];
            x0 += x1;
            x1 = (x1 << r) | (x1 >> (32 - r));
            x1 ^= x0;
        }
        x0 += ks[(i + 1) % 3];
        x1 += ks[(i + 2) % 3] + (uint32_t)(i + 1);
    }
    o0 = x0; o1 = x1;
}

__device__ __forceinline__ float bits_to_normal(uint32_t b) {
    float f = __uint_as_float((b >> 9) | 0x3F800000u) - 1.0f;
    const float lo = __uint_as_float(0xBF7FFFFFu);
    float u = fmaxf(lo, f * 2.0f + lo);
    return 1.41421356237309504880f * erfinvf(u);
}

// ---------------- po_k: prep (673 blocks) + onehot K-split GEMM (1024 blocks) --
// flat block id:
// [0,320)   transposes   [320,576) row dots   [576] c0   [577,641) cnt
// [641,673) G = Wp @ Wd2^T (MFMA)
// [673,1697) onehot partials: f2=f-673 -> bx=f2&3, mc=(f2>>2)&3, b=f2>>4
__global__ __launch_bounds__(256) void po_k(
    const float* __restrict__ Wp, const float* __restrict__ Wa1,
    const float* __restrict__ Wa2, const float* __restrict__ Wd1,
    const float* __restrict__ Wd2, const float* __restrict__ bp,
    const float* __restrict__ bd2, const int* __restrict__ y,
    const float* __restrict__ xc,
    unsigned short* __restrict__ WpTb, unsigned short* __restrict__ Wa1Tb,
    unsigned short* __restrict__ Wa2Tb, unsigned short* __restrict__ WdT1b,
    unsigned short* __restrict__ Gtb,
    float* __restrict__ bv, float* __restrict__ w2bp,
    float* __restrict__ c0, float* __restrict__ cnt,
    float* __restrict__ Apart)
{
    __shared__ __align__(16) char sm[24576];
    __shared__ int lc[256];
    __shared__ float ws4[4];
    const int f = blockIdx.x;
    const int tid = threadIdx.x;

    if (f < 320) {  // ---- transpose fp32 [512 x C] -> bf16 [C x 512]
        float (*T)[65] = reinterpret_cast<float(*)[65]>(sm);
        const float* src; unsigned short* dst; int C, t, xb, yb;
        if (f < 64)       { src = Wp;  dst = WpTb;  C = 512;  t = f;       xb = t & 7;  yb = t >> 3; }
        else if (f < 128) { src = Wa1; dst = Wa1Tb; C = 512;  t = f - 64;  xb = t & 7;  yb = t >> 3; }
        else if (f < 256) { src = Wa2; dst = Wa2Tb; C = 1024; t = f - 128; xb = t & 15; yb = t >> 4; }
        else              { src = Wd1; dst = WdT1b; C = 512;  t = f - 256; xb = t & 7;  yb = t >> 3; }
        const int r0 = yb * 64, cc0 = xb * 64;
        const int rr = tid >> 4, cc = (tid & 15) * 4;
#pragma unroll
        for (int l = 0; l < 4; l++) {
            int row = rr + l * 16;
            float4 v = *(const float4*)&src[(size_t)(r0 + row) * C + cc0 + cc];
            T[row][cc] = v.x; T[row][cc+1] = v.y; T[row][cc+2] = v.z; T[row][cc+3] = v.w;
        }
        __syncthreads();
#pragma unroll
        for (int l = 0; l < 4; l++) {
            int n = rr + l * 16;
            uint2 u;
            u.x = cvt2(T[cc][n], T[cc+1][n]);
            u.y = cvt2(T[cc+2][n], T[cc+3][n]);
            *(uint2*)&dst[(size_t)(cc0 + n) * 512 + r0 + cc] = u;
        }
    } else if (f < 576) {  // ---- row dots (wave per row)
        const float* W = (f < 448) ? Wp : Wd2;
        const float* v = (f < 448) ? bd2 : bp;
        float* o = (f < 448) ? bv : w2bp;
        int t = (f < 448) ? f - 320 : f - 448;
        int wave = tid >> 6, lane = tid & 63;
        int r = t * 4 + wave;
        const float* row = W + (size_t)r * 512 + lane * 8;
        float4 x0 = *(const float4*)row;
        float4 x1 = *(const float4*)(row + 4);
        float4 v0 = *(const float4*)&v[lane * 8];
        float4 v1 = *(const float4*)&v[lane * 8 + 4];
        float s = x0.x*v0.x + x0.y*v0.y + x0.z*v0.z + x0.w*v0.w
                + x1.x*v1.x + x1.y*v1.y + x1.z*v1.z + x1.w*v1.w;
#pragma unroll
        for (int off = 32; off > 0; off >>= 1) s += __shfl_down(s, off, 64);
        if (lane == 0) o[r] = s;
    } else if (f == 576) {  // ---- c0 = bp . bd2
        float s = bp[tid] * bd2[tid] + bp[tid + 256] * bd2[tid + 256];
#pragma unroll
        for (int off = 32; off > 0; off >>= 1) s += __shfl_down(s, off, 64);
        int wave = tid >> 6, lane = tid & 63;
        if (lane == 0) ws4[wave] = s;
        __syncthreads();
        if (tid == 0) c0[0] = ws4[0] + ws4[1] + ws4[2] + ws4[3];
    } else if (f < 641) {  // ---- class counts, exact int atomics
        int b = f - 577;
        if (tid < 32) lc[tid] = 0;
        __syncthreads();
        for (int m = tid; m < 1000; m += 256)
            atomicAdd(&lc[y[b * 1000 + m]], 1);
        __syncthreads();
        if (tid < 20) cnt[b * 20 + tid] = (float)lc[tid];
    } else if (f < 673) {  // ---- G = Wp @ Wd2^T (MFMA)
        unsigned short* As = (unsigned short*)sm;            // 64x64
        unsigned short* Bs = (unsigned short*)(sm + 8192);   // 128x64
        const int g = f - 641;
        const int lane = tid & 63, w = tid >> 6;
        const int row0 = (g >> 2) * 64, col0 = (g & 3) * 128;
        f32x4 acc[4][2] = {};
        for (int k0 = 0; k0 < 512; k0 += 64) {
            {
                int row = tid >> 2, cs = (tid & 3) * 16;
                int swz = (row & 7) << 4;
                const float* src = Wp + (size_t)(row0 + row) * 512 + k0 + cs;
#pragma unroll
                for (int j = 0; j < 2; j++) {
                    float4 v0 = *(const float4*)(src + j * 8);
                    float4 v1 = *(const float4*)(src + j * 8 + 4);
                    uint4 u;
                    u.x = cvt2(v0.x, v0.y); u.y = cvt2(v0.z, v0.w);
                    u.z = cvt2(v1.x, v1.y); u.w = cvt2(v1.z, v1.w);
                    *(uint4*)((char*)As + row * 128 + (((cs + j * 8) * 2) ^ swz)) = u;
                }
            }
            {
                int row = tid >> 1, cs = (tid & 1) * 32;
                int swz = (row & 7) << 4;
                const float* src = Wd2 + (size_t)(col0 + row) * 512 + k0 + cs;
#pragma unroll
                for (int j = 0; j < 4; j++) {
                    float4 v0 = *(const float4*)(src + j * 8);
                    float4 v1 = *(const float4*)(src + j * 8 + 4);
                    uint4 u;
                    u.x = cvt2(v0.x, v0.y); u.y = cvt2(v0.z, v0.w);
                    u.z = cvt2(v1.x, v1.y); u.w = cvt2(v1.z, v1.w);
                    *(uint4*)((char*)Bs + row * 128 + (((cs + j * 8) * 2) ^ swz)) = u;
                }
            }
            __syncthreads();
#pragma unroll
            for (int ks = 0; ks < 2; ks++) {
                short8 a[4], bb[2];
#pragma unroll
                for (int mi = 0; mi < 4; mi++) {
                    int r = mi * 16 + (lane & 15);
                    a[mi] = *(const short8*)((const char*)As + r * 128 +
                              (((ks * 32 + (lane >> 4) * 8) * 2) ^ ((r & 7) << 4)));
                }
#pragma unroll
                for (int ni = 0; ni < 2; ni++) {
                    int n = w * 32 + ni * 16 + (lane & 15);
                    bb[ni] = *(const short8*)((const char*)Bs + n * 128 +
                              (((ks * 32 + (lane >> 4) * 8) * 2) ^ ((n & 7) << 4)));
                }
#pragma unroll
                for (int mi = 0; mi < 4; mi++)
#pragma unroll
                    for (int ni = 0; ni < 2; ni++)
                        acc[mi][ni] = __builtin_amdgcn_mfma_f32_16x16x32_bf16(a[mi], bb[ni], acc[mi][ni], 0, 0, 0);
            }
            __syncthreads();
        }
#pragma unroll
        for (int mi = 0; mi < 4; mi++)
#pragma unroll
            for (int ni = 0; ni < 2; ni++) {
                int c = col0 + w * 32 + ni * 16 + (lane & 15);
#pragma unroll
                for (int j = 0; j < 4; j++) {
                    int r = row0 + mi * 16 + (lane >> 4) * 4 + j;
                    Gtb[(size_t)r * 512 + c] = f2bfu(acc[mi][ni][j]);
                }
            }
    } else {  // ---- onehot K-split partials
        unsigned short* Xs = (unsigned short*)sm;  // 128x64 bf16, 16 KB
        int* ys = lc;                               // reuse (256 ints)
        const int f2 = f - 673;
        const int chb = (f2 & 3) * 128;
        const int mc = (f2 >> 2) & 3;
        const int b = f2 >> 4;
        const int m00 = mc * 256;
        const int lane = tid & 63, w = tid >> 6;
        const int chs = w * 32;
        {
            int mg = m00 + tid;
            ys[tid] = (mg < 1000) ? y[b * 1000 + mg] : -1;
        }
        f32x4 acc[2][2] = {};
        for (int step = 0; step < 4; step++) {
            const int k0 = step * 64;
            int m = m00 + k0 + lane; if (m > 999) m = 999;
            const float* src = xc + ((size_t)b * 1000 + m) * 512 + chb + chs;
            float x[32];
#pragma unroll
            for (int j8 = 0; j8 < 8; j8++) {
                float4 v = *(const float4*)(src + j8 * 4);
                x[j8*4+0]=v.x; x[j8*4+1]=v.y; x[j8*4+2]=v.z; x[j8*4+3]=v.w;
            }
            __syncthreads();
#pragma unroll
            for (int j = 0; j < 32; j++) {
                int ch = chs + j;
                *(unsigned short*)((char*)Xs + ch * 128 + ((lane * 2) ^ ((ch & 7) << 4)))
                    = f2bfu(x[j]);
            }
            __syncthreads();
#pragma unroll
            for (int ks = 0; ks < 2; ks++) {
                int kb = ks * 32 + (lane >> 4) * 8;
                int4 yv0 = *(const int4*)&ys[k0 + kb];
                int4 yv1 = *(const int4*)&ys[k0 + kb + 4];
                int ya[8] = {yv0.x, yv0.y, yv0.z, yv0.w, yv1.x, yv1.y, yv1.z, yv1.w};
                short8 a[2];
#pragma unroll
                for (int mi = 0; mi < 2; mi++) {
                    int cls = mi * 16 + (lane & 15);
#pragma unroll
                    for (int e = 0; e < 8; e++)
                        a[mi][e] = (short)((ya[e] == cls) ? 0x3F80 : 0);
                }
                short8 bb[2];
#pragma unroll
                for (int ni = 0; ni < 2; ni++) {
                    int ch = chs + ni * 16 + (lane & 15);
                    bb[ni] = *(const short8*)((const char*)Xs + ch * 128 +
                               ((kb * 2) ^ ((ch & 7) << 4)));
                }
#pragma unroll
                for (int mi = 0; mi < 2; mi++)
#pragma unroll
                    for (int ni = 0; ni < 2; ni++)
                        acc[mi][ni] = __builtin_amdgcn_mfma_f32_16x16x32_bf16(a[mi], bb[ni], acc[mi][ni], 0, 0, 0);
            }
        }
        float* dst = Apart + (size_t)mc * 655360;
#pragma unroll
        for (int mi = 0; mi < 2; mi++) {
#pragma unroll
            for (int ni = 0; ni < 2; ni++) {
                int ch = chb + chs + ni * 16 + (lane & 15);
#pragma unroll
                for (int j = 0; j < 4; j++) {
                    int cls = mi * 16 + (lane >> 4) * 4 + j;
                    if (cls < 20)
                        dst[((size_t)b * 20 + cls) * 512 + ch] = acc[mi][ni][j];
                }
            }
        }
    }
}

// ---------------- unified bf16 MFMA GEMM, MTx128 tile, K=512 ----------------
template <int EPI, int MT, int A4>
__global__ __launch_bounds__(256) void gm2_k(const unsigned short* __restrict__ Abf,
                                             const unsigned short* __restrict__ Bbf,
                                             const float* __restrict__ bias,
                                             const float* __restrict__ extra,
                                             unsigned short* __restrict__ C0,
                                             float* __restrict__ F0,
                                             float* __restrict__ F1,
                                             int Nn) {
    __shared__ unsigned short As[MT * 64];
    __shared__ unsigned short Bs[128 * 64];
    const int tid = threadIdx.x;
    const int lane = tid & 63, w = tid >> 6;
    const int row0 = blockIdx.y * MT, col0 = blockIdx.x * 128;
    f32x4 acc[MT / 16][2] = {};
    for (int k0 = 0; k0 < 512; k0 += 64) {
        if constexpr (MT == 64) {
            int row = tid >> 2, cs = (tid & 3) * 16;
            int swz = (row & 7) << 4;
            const unsigned short* src = Abf + (size_t)(row0 + row) * 512 + k0 + cs;
#pragma unroll
            for (int j = 0; j < 2; j++) {
                uint4 u = *(const uint4*)(src + j * 8);
                *(uint4*)((char*)As + row * 128 + (((cs + j * 8) * 2) ^ swz)) = u;
            }
        } else {
            int row = tid >> 3, cs = (tid & 7) * 8;
            int swz = (row & 7) << 4;
            uint4 u;
            if constexpr (A4) {
                const float* p = (const float*)Abf + (size_t)(row0 + row) * 512 + k0 + cs;
                float4 s0 = *(const float4*)p;
                float4 s1 = *(const float4*)(p + 4);
#pragma unroll
                for (int q = 1; q < 4; q++) {
                    const float* pp = p + (size_t)q * 655360;
                    float4 v0 = *(const float4*)pp, v1 = *(const float4*)(pp + 4);
                    s0.x += v0.x; s0.y += v0.y; s0.z += v0.z; s0.w += v0.w;
                    s1.x += v1.x; s1.y += v1.y; s1.z += v1.z; s1.w += v1.w;
                }
                u.x = cvt2(s0.x, s0.y); u.y = cvt2(s0.z, s0.w);
                u.z = cvt2(s1.x, s1.y); u.w = cvt2(s1.z, s1.w);
            } else {
                u = *(const uint4*)(Abf + (size_t)(row0 + row) * 512 + k0 + cs);
            }
            *(uint4*)((char*)As + row * 128 + ((cs * 2) ^ swz)) = u;
        }
        {
            int row = tid >> 1, cs = (tid & 1) * 32;
            int swz = (row & 7) << 4;
            const unsigned short* src = Bbf + (size_t)(col0 + row) * 512 + k0 + cs;
#pragma unroll
            for (int j = 0; j < 4; j++) {
                uint4 u = *(const uint4*)(src + j * 8);
                *(uint4*)((char*)Bs + row * 128 + (((cs + j * 8) * 2) ^ swz)) = u;
            }
        }
        __syncthreads();
#pragma unroll
        for (int ks = 0; ks < 2; ks++) {
            short8 a[MT / 16], bb[2];
#pragma unroll
            for (int mi = 0; mi < MT / 16; mi++) {
                int r = mi * 16 + (lane & 15);
                a[mi] = *(const short8*)((const char*)As + r * 128 +
                          (((ks * 32 + (lane >> 4) * 8) * 2) ^ ((r & 7) << 4)));
            }
#pragma unroll
            for (int ni = 0; ni < 2; ni++) {
                int n = w * 32 + ni * 16 + (lane & 15);
                bb[ni] = *(const short8*)((const char*)Bs + n * 128 +
                          (((ks * 32 + (lane >> 4) * 8) * 2) ^ ((n & 7) << 4)));
            }
#pragma unroll
            for (int mi = 0; mi < MT / 16; mi++)
#pragma unroll
                for (int ni = 0; ni < 2; ni++)
                    acc[mi][ni] = __builtin_amdgcn_mfma_f32_16x16x32_bf16(a[mi], bb[ni], acc[mi][ni], 0, 0, 0);
        }
        __syncthreads();
    }
#pragma unroll
    for (int mi = 0; mi < MT / 16; mi++) {
#pragma unroll
        for (int ni = 0; ni < 2; ni++) {
            int c = col0 + w * 32 + ni * 16 + (lane & 15);
            float bvv = bias ? bias[c] : 0.f;
#pragma unroll
            for (int j = 0; j < 4; j++) {
                int r = row0 + mi * 16 + (lane >> 4) * 4 + j;
                float v = acc[mi][ni][j];
                if (EPI == 0) {
                    v += bvv;
                    C0[(size_t)r * Nn + c] = f2bfu(v);
                } else if (EPI == 1) {
                    v += extra[r] * bvv;
                    C0[(size_t)r * Nn + c] = f2bfu(fmaxf(v, 0.f));
                } else if (EPI == 2) {
                    C0[(size_t)r * Nn + c] = f2bfu(gelu_f(v + bvv));
                } else {
                    v += bvv;
                    if (c < 512) F0[(size_t)r * 512 + c] = v;
                    else F1[(size_t)r * 512 + (c - 512)] = 0.01f + 0.99f * softplus_f(v);
                }
            }
        }
    }
}

// ---------------- z = mu + scale*eps ; emits fp32 z + bf16 zb ----------------
__global__ __launch_bounds__(256) void z2_k(const float* __restrict__ mu,
                                            const float* __restrict__ sc,
                                            float* __restrict__ z,
                                            unsigned short* __restrict__ zb) {
    const uint32_t NH = 2621440u;
    uint32_t i = blockIdx.x * 256u + threadIdx.x;
    if (i >= NH) return;
    uint32_t t0 = 2u * i;
    uint32_t o0, o1, p0, p1;
    threefry2x32(0u, 42u, 0u, t0, o0, o1);
    threefry2x32(0u, 42u, 0u, t0 + 1u, p0, p1);
    uint32_t r0 = t0 % 655360u;
    float2 mv = *(const float2*)&mu[r0];
    float2 sv = *(const float2*)&sc[r0];
    float z0 = mv.x + sv.x * bits_to_normal(o0 ^ o1);
    float z1 = mv.y + sv.y * bits_to_normal(p0 ^ p1);
    float2 zo; zo.x = z0; zo.y = z1;
    *(float2*)&z[t0] = zo;
    *(uint32_t*)&zb[t0] = cvt2(z0, z1);
}

// ---------------- wgv_k: fused Wg = gelu(z@Wd1+bd1) [LDS], V = Wg@G + bv,
//                  beta[r] = Wg[r,:].w2bp + c0.  512 thr (8 waves), 160 blocks.
__global__ __launch_bounds__(512) void wgv_k(const unsigned short* __restrict__ zb,
                                             const unsigned short* __restrict__ Wd1T,
                                             const unsigned short* __restrict__ Gt,
                                             const float* __restrict__ bd1,
                                             const float* __restrict__ bv,
                                             const float* __restrict__ w2bp,
                                             const float* __restrict__ c0,
                                             unsigned short* __restrict__ Vbf,
                                             float* __restrict__ beta) {
    __shared__ unsigned short Wg[64 * 512];  // 64 KB, row stride 1024 B, XOR-swz
    __shared__ unsigned short As[64 * 64];   // 8 KB z staging
    const int r0 = blockIdx.x * 64;
    const int tid = threadIdx.x, lane = tid & 63, w = tid >> 6;   // 8 waves
    const int col0 = w * 64;                 // wave's 64-col tile

    // ---- phase 1: Wg tile (B-frags direct from global Wd1T, L2-resident) ----
    f32x4 acc[4][4] = {};
    for (int k0 = 0; k0 < 512; k0 += 64) {
        {
            int row = tid >> 3, cs = (tid & 7) * 8;
            int swz = (row & 7) << 4;
            uint4 u = *(const uint4*)(zb + (size_t)(r0 + row) * 512 + k0 + cs);
            *(uint4*)((char*)As + row * 128 + ((cs * 2) ^ swz)) = u;
        }
        __syncthreads();
#pragma unroll
        for (int ks = 0; ks < 2; ks++) {
            int kb = ks * 32 + (lane >> 4) * 8;
            short8 a[4], bb[4];
#pragma unroll
            for (int mi = 0; mi < 4; mi++) {
                int r = mi * 16 + (lane & 15);
                a[mi] = *(const short8*)((const char*)As + r * 128 +
                          ((kb * 2) ^ ((r & 7) << 4)));
            }
#pragma unroll
            for (int ni = 0; ni < 4; ni++) {
                int n = col0 + ni * 16 + (lane & 15);
                bb[ni] = *(const short8*)(Wd1T + (size_t)n * 512 + k0 + kb);
            }
#pragma unroll
            for (int mi = 0; mi < 4; mi++)
#pragma unroll
                for (int ni = 0; ni < 4; ni++)
                    acc[mi][ni] = __builtin_amdgcn_mfma_f32_16x16x32_bf16(a[mi], bb[ni], acc[mi][ni], 0, 0, 0);
        }
        __syncthreads();
    }
    // epilogue: gelu -> Wg LDS (swizzled)
#pragma unroll
    for (int mi = 0; mi < 4; mi++) {
#pragma unroll
        for (int ni = 0; ni < 4; ni++) {
            int c = col0 + ni * 16 + (lane & 15);
            float bvv = bd1[c];
#pragma unroll
            for (int j = 0; j < 4; j++) {
                int r = mi * 16 + (lane >> 4) * 4 + j;
                float v = gelu_f(acc[mi][ni][j] + bvv);
                *(unsigned short*)((char*)Wg + r * 1024 + ((c * 2) ^ ((r & 7) << 4)))
                    = f2bfu(v);
            }
        }
    }
    __syncthreads();

    // ---- beta from Wg LDS ----
    {
        int row = tid >> 3, p = tid & 7;
        const char* base = (const char*)Wg + row * 1024;
        int swz = (row & 7) << 4;
        float s = 0.f;
#pragma unroll
        for (int j = 0; j < 64; j++) {
            int c = p * 64 + j;
            s += bfu2f(*(const unsigned short*)(base + ((c * 2) ^ swz))) * w2bp[c];
        }
#pragma unroll
        for (int off = 4; off > 0; off >>= 1) s += __shfl_down(s, off, 64);
        if (p == 0) beta[r0 + row] = s + c0[0];
    }

    // ---- phase 2: V = Wg @ G + bv ----
    f32x4 acc2[4][4] = {};
    for (int k0 = 0; k0 < 512; k0 += 64) {
#pragma unroll
        for (int ks = 0; ks < 2; ks++) {
            int kb = ks * 32 + (lane >> 4) * 8;
            short8 a[4], bb[4];
#pragma unroll
            for (int mi = 0; mi < 4; mi++) {
                int r = mi * 16 + (lane & 15);
                a[mi] = *(const short8*)((const char*)Wg + r * 1024 +
                          (((k0 + kb) * 2) ^ ((r & 7) << 4)));
            }
#pragma unroll
            for (int ni = 0; ni < 4; ni++) {
                int n = col0 + ni * 16 + (lane & 15);
                bb[ni] = *(const short8*)(Gt + (size_t)n * 512 + k0 + kb);
            }
#pragma unroll
            for (int mi = 0; mi < 4; mi++)
#pragma unroll
                for (int ni = 0; ni < 4; ni++)
                    acc2[mi][ni] = __builtin_amdgcn_mfma_f32_16x16x32_bf16(a[mi], bb[ni], acc2[mi][ni], 0, 0, 0);
        }
    }
#pragma unroll
    for (int mi = 0; mi < 4; mi++) {
#pragma unroll
        for (int ni = 0; ni < 4; ni++) {
            int c = col0 + ni * 16 + (lane & 15);
            float bvv = bv[c];
#pragma unroll
            for (int j = 0; j < 4; j++) {
                int r = r0 + mi * 16 + (lane >> 4) * 4 + j;
                Vbf[(size_t)r * 512 + c] = f2bfu(acc2[mi][ni][j] + bvv);
            }
        }
    }
}

// ---------------- logits v4: dbuf V staging, 1 barrier/k-step ---------------
__global__ __launch_bounds__(512) void logits_mfma4_k(const float* __restrict__ Xq,
                                                      const unsigned short* __restrict__ Vb,
                                                      const float* __restrict__ beta,
                                                      float* __restrict__ out) {
    __shared__ unsigned short Vs[2][160 * 64];
    __shared__ float bs[160];
    const int u = blockIdx.x + 8 * blockIdx.y;
    const int xcd = u & 7, idx = u >> 3;
    const int b = (idx & 7) * 8 + xcd;
    const int qh = idx >> 3;
    const int tid = threadIdx.x, lane = tid & 63, w = tid >> 6;
    const int wq = w >> 1, wn = w & 1;

    if (tid < 160) {
        int s = tid / 20, n = tid - s * 20;
        bs[tid] = beta[(size_t)(s * 64 + b) * 20 + n];
    }

    auto stageV = [&](int buf, int k0) {
        for (int c = tid; c < 640; c += 512) {
            int row = c >> 2, off = (c & 3) * 32;
            int sdiv = row / 20;
            int row_g = row + sdiv * 1260 + b * 20;
            const unsigned short* src = Vb + (size_t)row_g * 512 + k0 + (c & 3) * 16;
            uint4 u0 = *(const uint4*)src;
            uint4 u1 = *(const uint4*)(src + 8);
            int swz = (row & 7) << 4;
            char* base = (char*)&Vs[buf][0] + row * 128;
            *(uint4*)(base + (off ^ swz)) = u0;
            *(uint4*)(base + ((off + 16) ^ swz)) = u1;
        }
    };

    const int klane = (lane >> 4) * 8;
    const float* xp[2];
    int qb[2];
#pragma unroll
    for (int qs = 0; qs < 2; qs++) {
        qb[qs] = qh * 128 + wq * 32 + qs * 16;
        int qr = qb[qs] + (lane & 15);
        if (qr > 999) qr = 999;
        xp[qs] = Xq + ((size_t)b * 1000 + qr) * 512 + klane;
    }
    int vrow[5], vswz[5];
#pragma unroll
    for (int nf = 0; nf < 5; nf++) {
        int rr = wn * 80 + nf * 16 + (lane & 15);
        vrow[nf] = rr * 128;
        vswz[nf] = (rr & 7) << 4;
    }

    stageV(0, 0);
    __syncthreads();

    f32x4 acc[2][5] = {};
    int cur = 0;
    for (int step = 0; step < 8; step++) {
        const int k0 = step * 64;
        if (step < 7) stageV(cur ^ 1, k0 + 64);
        const char* vbase = (const char*)&Vs[cur][0];
#pragma unroll
        for (int ks = 0; ks < 2; ks++) {
            int kb = (ks * 32 + klane) * 2;
            short8 bf[5];
#pragma unroll
            for (int nf = 0; nf < 5; nf++)
                bf[nf] = *(const short8*)(vbase + vrow[nf] + (kb ^ vswz[nf]));
            short8 af[2];
#pragma unroll
            for (int qs = 0; qs < 2; qs++) {
                const float* p = xp[qs] + k0 + ks * 32;
                float4 v0 = *(const float4*)p;
                float4 v1 = *(const float4*)(p + 4);
                uint4 uu;
                uu.x = cvt2(v0.x, v0.y); uu.y = cvt2(v0.z, v0.w);
                uu.z = cvt2(v1.x, v1.y); uu.w = cvt2(v1.z, v1.w);
                __builtin_memcpy(&af[qs], &uu, 16);
            }
#pragma unroll
            for (int qs = 0; qs < 2; qs++)
#pragma unroll
                for (int nf = 0; nf < 5; nf++)
                    acc[qs][nf] = __builtin_amdgcn_mfma_f32_16x16x32_bf16(af[qs], bf[nf], acc[qs][nf], 0, 0, 0);
        }
        __syncthreads();
        cur ^= 1;
    }

#pragma unroll
    for (int nf = 0; nf < 5; nf++) {
        int rl = wn * 80 + nf * 16 + (lane & 15);
        int s = rl / 20, n = rl - s * 20;
        float bb = bs[rl];
        size_t ob = (size_t)(s * 64 + b) * 20000;
#pragma unroll
        for (int qs = 0; qs < 2; qs++) {
#pragma unroll
            for (int j = 0; j < 4; j++) {
                int q = qb[qs] + (lane >> 4) * 4 + j;
                if (q < 1000)
                    out[ob + (size_t)q * 20 + n] = acc[qs][nf][j] + bb;
            }
        }
    }
}

extern "C" void kernel_launch(void* const* d_in, const int* in_sizes, int n_in,
                              void* d_out, int out_size, void* d_ws, size_t ws_size,
                              hipStream_t stream) {
    const float* x_context = (const float*)d_in[0];
    const int*   y_context = (const int*)d_in[1];
    const float* x_query   = (const float*)d_in[2];
    const float* Wp  = (const float*)d_in[3];
    const float* bp  = (const float*)d_in[4];
    const float* Wa1 = (const float*)d_in[5];
    const float* ba1 = (const float*)d_in[6];
    const float* Wa2 = (const float*)d_in[7];
    const float* ba2 = (const float*)d_in[8];
    const float* Wd1 = (const float*)d_in[9];
    const float* bd1 = (const float*)d_in[10];
    const float* Wd2 = (const float*)d_in[11];
    const float* bd2 = (const float*)d_in[12];

    float* out    = (float*)d_out;
    float* logits = out;                   // 10,240,000 f
    float* z      = out + 10240000;        // 5,242,880 f
    float* mu     = out + 15482880;        // 655,360 f
    float* sc     = out + 16138240;        // 655,360 f

    // workspace layout
    float* ws   = (float*)d_ws;
    float* cnt  = ws;                       // 1,280 f
    float* beta = cnt + 1280;               // 10,240 f
    float* bv   = beta + 10240;             // 512 f
    float* w2bp = bv + 512;                 // 512 f
    float* c0   = w2bp + 512;               // 1 f (+pad)
    unsigned short* WpTb  = (unsigned short*)(c0 + 63);       // 262,144 sh
    unsigned short* Wa1Tb = WpTb + 262144;                    // 262,144 sh
    unsigned short* Wa2Tb = Wa1Tb + 262144;                   // 524,288 sh
    unsigned short* WdT1b = Wa2Tb + 524288;                   // 262,144 sh
    unsigned short* Gtb   = WdT1b + 262144;                   // 262,144 sh
    unsigned short* combb = Gtb + 262144;                     // 655,360 sh
    unsigned short* hb    = combb + 655360;                   // 655,360 sh
    unsigned short* zb    = hb + 655360;                      // 5,242,880 sh
    unsigned short* Vbf   = zb + 5242880;                     // 5,242,880 sh
    float* big = (float*)(Vbf + 5242880);   // 4x655,360 f onehot partials

    // 0) prep + G + onehot partials, one launch (all read only inputs)
    po_k<<<dim3(1697), 256, 0, stream>>>(Wp, Wa1, Wa2, Wd1, Wd2, bp, bd2, y_context,
                                         x_context,
                                         WpTb, Wa1Tb, Wa2Tb, WdT1b, Gtb,
                                         bv, w2bp, c0, cnt, big);
    // 3) comb = relu(A@Wp + cnt*bp)   [A4: inline 4-way partial reduce]
    gm2_k<1, 32, 1><<<dim3(4, 40), 256, 0, stream>>>((const unsigned short*)big, WpTb, bp, cnt, combb, nullptr, nullptr, 512);
    // 4) h = gelu(comb@Wa1 + ba1)
    gm2_k<2, 32, 0><<<dim3(4, 40), 256, 0, stream>>>(combb, Wa1Tb, ba1, nullptr, hb, nullptr, nullptr, 512);
    // 5) stats = h@Wa2 + ba2 -> mu, scale (fp32 outputs)
    gm2_k<3, 32, 0><<<dim3(8, 40), 256, 0, stream>>>(hb, Wa2Tb, ba2, nullptr, nullptr, mu, sc, 1024);
    // 6) z (fp32 out) + zb (bf16)
    z2_k<<<dim3(10240), 256, 0, stream>>>(mu, sc, z, zb);
    // 7+8+9) Wg (LDS) -> V, beta — fused
    wgv_k<<<dim3(160), 512, 0, stream>>>(zb, WdT1b, Gtb, bd1, bv, w2bp, c0, Vbf, beta);
    // 10) logits
    logits_mfma4_k<<<dim3(8, 64), 512, 0, stream>>>(x_query, Vbf, beta, logits);
}